// Round 8
// baseline (220.953 us; speedup 1.0000x reference)
//
#include <hip/hip_runtime.h>

// CrossScaleAttention: out = softmax(l2n(Q) l2n(K)^T * 32^-0.5) V
// B=4, Nq=Nk=4096, D=256, fp32 in/out.
// |scores| <= 0.1768 => no online max: O += exp(S) V, l += rowsum, divide at end.
// R15: STRUCTURAL rewrite (m214 pattern). R7-R14 proved the S->Plds->barrier->O
//   structure caps MfmaUtil at ~30% regardless of occupancy/schedule. New form:
//   swapped 32x32 QK^T (A=K, B=Q) keeps each lane's P row lane-local ->
//   softmax + bf16-pack fully in registers (v_cvt_pk_bf16_f32 + 
//   v_permlane32_swap_b32, m214-verified recipe) -> PV consumes register
//   A-frags directly. Deletes Plds, the mid barrier, all P LDS traffic; waves
//   are independent between K-stage barriers (1 barrier/tile).
//   Geometry: 4 waves x 32 q-rows (BM=128), KVBLK=32, KSPLIT=4, grid 512 =
//   2 independent blocks/CU; K staged in LDS dbuf (16KB/tile), V B-frags from
//   global (proven vf pattern); Q normalized in a 2-pass register prologue.
//   All MFMA operand layouts anchored to the currently-passing kernel's
//   pf/vf/O-store conventions (A row=l&31, k=(l>>5)*8+j; B k=(l>>5)*8+j,
//   col=l&31; C col=l&31, row=(reg&3)+8*(reg>>2)+4*(l>>5)).

#define NQ 4096
#define DIM 256
#define NROWS 16384      // B*NQ
#define BM 128           // q rows per block (4 waves x 32)
#define BN 32            // keys per tile
#define KSPLIT 4
#define NITER 32         // (4096/KSPLIT)/BN

typedef __attribute__((ext_vector_type(8))) short bf16x8;
typedef __attribute__((ext_vector_type(16))) float f32x16;

__device__ __forceinline__ unsigned short f2bf(float f) {
  unsigned int u = __float_as_uint(f);
  u += 0x7fffu + ((u >> 16) & 1u);            // RNE
  return (unsigned short)(u >> 16);
}

__device__ __forceinline__ float bf2f(unsigned short h) {
  return __uint_as_float((unsigned int)h << 16);
}

__device__ __forceinline__ void gload16(const void* g, void* l) {
  __builtin_amdgcn_global_load_lds(
      (const __attribute__((address_space(1))) unsigned int*)g,
      (__attribute__((address_space(3))) unsigned int*)l, 16, 0, 0);
}

// ---------------------------------------------------------------------------
// prep:
//  [0,512):    K 32-row tiles -> normalize -> slot-major Kfm
//              [tile32][slot=d/8: 32][n: 32][8]  (A-frag linear order)
//  [512,1536): V 16-row tiles -> B-frag-major Vfm via LDS transpose (unchanged).
// ---------------------------------------------------------------------------
__global__ __launch_bounds__(256) void prep(
    const float* __restrict__ K, const float* __restrict__ V,
    unsigned short* __restrict__ Kfm, unsigned short* __restrict__ Vfm)
{
  __shared__ unsigned short vt[32 * 264];
  const int blk = blockIdx.x, tid = threadIdx.x;
  const int wave = tid >> 6, lane = tid & 63;
  if (blk < 512) {
    const int kt = blk;               // 32-row K tile
    #pragma unroll
    for (int i = 0; i < 8; i++) {
      const int r = wave*8 + i;       // 0..31 local row
      float4 v = *(const float4*)(K + ((size_t)kt*32 + r) * DIM + lane * 4);
      float ss = v.x*v.x + v.y*v.y + v.z*v.z + v.w*v.w;
      #pragma unroll
      for (int off = 1; off < 64; off <<= 1) ss += __shfl_xor(ss, off, 64);
      float scale = 1.0f / fmaxf(sqrtf(ss), 1e-12f);
      ushort4 o;
      o.x = f2bf(v.x*scale); o.y = f2bf(v.y*scale);
      o.z = f2bf(v.z*scale); o.w = f2bf(v.w*scale);
      *(ushort4*)(vt + r*264 + lane*4) = o;
    }
    __syncthreads();
    #pragma unroll
    for (int s = 0; s < 4; s++) {
      const int ch = tid + 256*s;          // 1024 chunks: slot c, row r
      const int c = ch >> 5, r = ch & 31;
      bf16x8 val = *(const bf16x8*)(vt + r*264 + c*8);
      *(bf16x8*)(Kfm + (size_t)kt*8192 + c*256 + r*8) = val;
    }
  } else {
    const int NS = blk - 512;
    #pragma unroll
    for (int i = 0; i < 4; i++) {
      const int e = tid + 256*i;
      const int nl = e >> 6, d = (e & 63) * 4;
      float4 v = *(const float4*)(V + ((size_t)NS*16 + nl)*DIM + d);
      ushort4 o;
      o.x = f2bf(v.x); o.y = f2bf(v.y); o.z = f2bf(v.z); o.w = f2bf(v.w);
      *(ushort4*)(vt + nl*264 + d) = o;
    }
    __syncthreads();
    #pragma unroll
    for (int i = 0; i < 2; i++) {
      const int ch = tid + 256*i;
      const int db = ch >> 6, ln = ch & 63;
      const int row0 = (ln >> 5) * 8, dd = db*32 + (ln & 31);
      ushort4 a, b;
      a.x = vt[(row0+0)*264 + dd]; a.y = vt[(row0+1)*264 + dd];
      a.z = vt[(row0+2)*264 + dd]; a.w = vt[(row0+3)*264 + dd];
      b.x = vt[(row0+4)*264 + dd]; b.y = vt[(row0+5)*264 + dd];
      b.z = vt[(row0+6)*264 + dd]; b.w = vt[(row0+7)*264 + dd];
      size_t base = ((size_t)(NS*8 + db)*64 + ln)*8;
      *(ushort4*)(Vfm + base)     = a;
      *(ushort4*)(Vfm + base + 4) = b;
    }
  }
}

// ---------------------------------------------------------------------------
// attn: grid=512, 256 thr (4 waves), 2 blocks/CU. blk&15 -> (b,ks): all blocks
// of a group land on one XCD (grid 512, 16 groups, stride-16 ≡ same blk&7) ->
// 0.5+0.5 MB K/V slice per group, 2 groups/XCD = 2MB in L2.
// Per tile: sync / stage(t+1) / S (16 ds_read + 16 MFMA, 2 acc chains) /
// in-register softmax (exp2, cvt_pk, permlane32_swap) / PV (16 vf + 16 MFMA).
// No mid-barrier. Each wave owns 32 q rows (m = lane&31), all n, all d.
// ---------------------------------------------------------------------------
__global__ __launch_bounds__(256, 2) void attn(
    const float* __restrict__ Qg,
    const unsigned short* __restrict__ Kfm,
    const unsigned short* __restrict__ Vfm,
    unsigned short* __restrict__ Opart, float* __restrict__ lpart)
{
  __shared__ unsigned short Klds[2][BN * DIM];   // 2 x 16 KB, slot-major

  const int tid = threadIdx.x, wave = tid >> 6, lane = tid & 63;
  const int l31 = lane & 31, hi = lane >> 5;
  const int blk = blockIdx.x;
  const int g = blk & 15, qt = blk >> 4;
  const int b = g >> 2, ks = g & 3;
  const int Rq0 = b*NQ + qt*BM;
  const int n0 = b*NQ + ks*(NQ/KSPLIT);
  const int m0 = Rq0 + wave*32 + l31;        // this lane's q row (hi pairs share it)

  // ---- prologue: 2-pass register normalize; Q B-frags (col=m, k=d-slot) ----
  // lane holds Q[m0][d = kg*16 + hi*8 + j]; l and l^32 hold complementary d.
  bf16x8 qf[16];
  {
    const float* qrow = Qg + (size_t)m0*DIM + hi*8;
    float ss = 0.f;
    #pragma unroll
    for (int kg = 0; kg < 16; kg++) {
      float4 a = *(const float4*)(qrow + kg*16);
      float4 c = *(const float4*)(qrow + kg*16 + 4);
      ss += a.x*a.x + a.y*a.y + a.z*a.z + a.w*a.w
          + c.x*c.x + c.y*c.y + c.z*c.z + c.w*c.w;
    }
    ss += __shfl_xor(ss, 32, 64);
    const float scale = (0.17677669529663687f * 1.4426950408889634f)  // SCALE*log2e
                        / fmaxf(sqrtf(ss), 1e-12f);
    #pragma unroll
    for (int kg = 0; kg < 16; kg++) {
      float4 a = *(const float4*)(qrow + kg*16);
      float4 c = *(const float4*)(qrow + kg*16 + 4);
      union { unsigned short u[8]; bf16x8 v; } o;
      o.u[0] = f2bf(a.x*scale); o.u[1] = f2bf(a.y*scale);
      o.u[2] = f2bf(a.z*scale); o.u[3] = f2bf(a.w*scale);
      o.u[4] = f2bf(c.x*scale); o.u[5] = f2bf(c.y*scale);
      o.u[6] = f2bf(c.z*scale); o.u[7] = f2bf(c.w*scale);
      qf[kg] = o.v;
    }
  }

  f32x16 oacc[8] = {};   // [db] d = db*32 + l31, m via reg formula
  float lacc = 0.f;

  auto stage = [&](int t) {
    const unsigned short* src = Kfm + ((size_t)(n0 >> 5) + t) * 8192;
    unsigned short* dst = &Klds[t & 1][0];
    #pragma unroll
    for (int c = 0; c < 4; c++)
      gload16(src + (wave*4 + c)*512 + lane*8, dst + (wave*4 + c)*512);
  };

  stage(0);

  for (int t = 0; t < NITER; t++) {
    __syncthreads();                   // stage(t) landed; buf[(t+1)&1] free
    if (t + 1 < NITER) stage(t + 1);   // covered by S+softmax+PV of tile t

    // ---- S^T = Khat Qhat^T : C[col=m=l31][row=n formula], 2 acc chains ----
    const unsigned short* kb = &Klds[t & 1][0];
    f32x16 sa = {}, sb = {};
    __builtin_amdgcn_s_setprio(1);
    #pragma unroll
    for (int kg = 0; kg < 16; kg++) {
      bf16x8 kf = *(const bf16x8*)(kb + ((kg*2 + hi)*32 + l31)*8);  // A: row=n, k=d
      if (kg & 1)
        sb = __builtin_amdgcn_mfma_f32_32x32x16_bf16(kf, qf[kg], sb, 0, 0, 0);
      else
        sa = __builtin_amdgcn_mfma_f32_32x32x16_bf16(kf, qf[kg], sa, 0, 0, 0);
    }
    __builtin_amdgcn_s_setprio(0);

    // ---- in-register softmax: p[reg] for n = (reg&3) + 8*(reg>>2) + 4*hi ----
    float p[16];
    #pragma unroll
    for (int r = 0; r < 16; r++)
      p[r] = __builtin_amdgcn_exp2f(sa[r] + sb[r]);
    #pragma unroll
    for (int r = 0; r < 16; r++) lacc += p[r];

    // pack to PV A-frags (row=m=l31, k-slot = n): cvt_pk pairs + permlane32_swap
    // (m214 r272 recipe): frag words j{0,1},{2,3},{4,5},{6,7} per 16-n group.
    auto mkfrag = [](const float* pp) -> bf16x8 {
      unsigned int a0, a1, b0, b1;
      asm("v_cvt_pk_bf16_f32 %0, %1, %2" : "=v"(a0) : "v"(pp[0]), "v"(pp[1]));
      asm("v_cvt_pk_bf16_f32 %0, %1, %2" : "=v"(b0) : "v"(pp[4]), "v"(pp[5]));
      asm("v_cvt_pk_bf16_f32 %0, %1, %2" : "=v"(a1) : "v"(pp[2]), "v"(pp[3]));
      asm("v_cvt_pk_bf16_f32 %0, %1, %2" : "=v"(b1) : "v"(pp[6]), "v"(pp[7]));
      asm volatile("v_permlane32_swap_b32 %0, %1" : "+v"(a0), "+v"(b0));
      asm volatile("v_permlane32_swap_b32 %0, %1" : "+v"(a1), "+v"(b1));
      union { unsigned int u[4]; bf16x8 v; } r;
      r.u[0] = a0; r.u[1] = a1; r.u[2] = b0; r.u[3] = b1;
      return r.v;
    };
    const bf16x8 pa0 = mkfrag(p);       // n 0..15
    const bf16x8 pa1 = mkfrag(p + 8);   // n 16..31

    // ---- O += P V : B = V[n][d] from Vfm (proven vf pattern) ----
    const int nb = (n0 + t*BN) >> 4;    // two 16-n halves: nb, nb+1
    #pragma unroll
    for (int db = 0; db < 8; db++) {
      bf16x8 v0 = *(const bf16x8*)(Vfm + ((size_t)((nb  )*8 + db)*64 + lane)*8);
      bf16x8 v1 = *(const bf16x8*)(Vfm + ((size_t)((nb+1)*8 + db)*64 + lane)*8);
      __builtin_amdgcn_s_setprio(1);
      oacc[db] = __builtin_amdgcn_mfma_f32_32x32x16_bf16(pa0, v0, oacc[db], 0, 0, 0);
      oacc[db] = __builtin_amdgcn_mfma_f32_32x32x16_bf16(pa1, v1, oacc[db], 0, 0, 0);
      __builtin_amdgcn_s_setprio(0);
    }
  }

  // ---- epilogue: row sums (lane pair l, l^32 hold complementary n) ----
  lacc += __shfl_xor(lacc, 32, 64);
  if (hi == 0)
    lpart[(size_t)ks*NROWS + Rq0 + wave*32 + l31] = lacc;

  // ---- epilogue: O stores (bf16), C layout col=d=l31, row m formula ----
  #pragma unroll
  for (int db = 0; db < 8; db++)
    #pragma unroll
    for (int reg = 0; reg < 16; reg++) {
      const int m = 4*hi + (reg & 3) + 8*(reg >> 2);
      Opart[((size_t)(ks*NROWS + Rq0 + wave*32 + m))*DIM + db*32 + l31]
          = f2bf(oacc[db][reg]);
    }
}

// ---------------------------------------------------------------------------
// combine: out = sum_s O_s / sum_s l_s over 4 slices, Opart in bf16
// ---------------------------------------------------------------------------
__global__ __launch_bounds__(256) void combine(
    const unsigned short* __restrict__ Opart, const float* __restrict__ lpart,
    float* __restrict__ out)
{
  const size_t idx = (size_t)blockIdx.x*256 + threadIdx.x;
  const size_t e = idx*4;
  const int R = (int)(e >> 8);
  float ls = 0.0f;
  #pragma unroll
  for (int i = 0; i < 4; i++) ls += lpart[(size_t)i*NROWS + R];
  float inv = 1.0f / ls;
  float4 o = {0.f, 0.f, 0.f, 0.f};
  #pragma unroll
  for (int s = 0; s < 4; s++) {
    ushort4 op = *(const ushort4*)(Opart + (size_t)s*NROWS*DIM + e);
    o.x += bf2f(op.x); o.y += bf2f(op.y);
    o.z += bf2f(op.z); o.w += bf2f(op.w);
  }
  o.x *= inv; o.y *= inv; o.z *= inv; o.w *= inv;
  *(float4*)(out + e) = o;
}

extern "C" void kernel_launch(void* const* d_in, const int* in_sizes, int n_in,
                              void* d_out, int out_size, void* d_ws, size_t ws_size,
                              hipStream_t stream) {
  const float* Q = (const float*)d_in[0];
  const float* K = (const float*)d_in[1];
  const float* V = (const float*)d_in[2];
  char* ws = (char*)d_ws;
  // ws layout: Kfm 8 MiB | Vfm 8 MiB | Opart(bf16) 32 MiB | lpart 256 KiB
  // total 48.3 MiB -- fits (R9's 48.5 MiB KS=4 branch ran on this harness).
  unsigned short* Kfm   = (unsigned short*)(ws);
  unsigned short* Vfm   = (unsigned short*)(ws + 8388608);
  unsigned short* Opart = (unsigned short*)(ws + 16777216);
  float* lpart = (float*)(ws + 16777216 + 33554432);

  prep<<<1536, 256, 0, stream>>>(K, V, Kfm, Vfm);
  attn<<<512, 256, 0, stream>>>(Q, Kfm, Vfm, Opart, lpart);
  combine<<<4096, 256, 0, stream>>>(Opart, lpart, (float*)d_out);
}

// Round 9
// 171.546 us; speedup vs baseline: 1.2880x; 1.2880x over previous
//
#include <hip/hip_runtime.h>

// CrossScaleAttention: out = softmax(l2n(Q) l2n(K)^T * 32^-0.5) V
// B=4, Nq=Nk=4096, D=256, fp32 in/out.
// |scores| <= 0.1768 => no online max: O += exp(S) V, l += rowsum, divide at end.
// R16: consolidation at the measured optimum. Nine structural/schedule theories
//   (R8-R15) bracketed the attn floor at ~91us for this decomposition; best
//   variant = R8 (dbuf Klds, stage-at-top, lgkm-only mid barrier: 90.6-91.1us).
//   This round: R8 attn verbatim + ONE certain micro-fix: pad the Q-staging
//   stride 256->264 ushorts. The constant SQ_LDS_BANK_CONFLICT=917504 across
//   R7-R14 is the prologue Q b128 reads (512B row stride = 16-way); R15's
//   register prologue measured exactly 0, confirming attribution. 528B stride
//   -> 2-way (free, m136). Padded rows spill into Klds buf1, first written by
//   stage(1) AFTER the Q-read barrier -> safe. prep/combine = R7 verbatim.

#define NQ 4096
#define DIM 256
#define NROWS 16384      // B*NQ
#define BM 64            // q rows per workgroup
#define BN 64            // keys per iteration
#define KSPLIT 2
#define NITER 32         // (4096/KSPLIT)/BN
#define PSTRIDE 68       // Plds row stride (ushorts): 64 + 4 pad
#define QSTRIDE 264      // Q staging row stride (ushorts): 256 + 8 pad (R16)

typedef __attribute__((ext_vector_type(8))) short bf16x8;
typedef __attribute__((ext_vector_type(4))) float f32x4;
typedef __attribute__((ext_vector_type(16))) float f32x16;

__device__ __forceinline__ unsigned short f2bf(float f) {
  unsigned int u = __float_as_uint(f);
  u += 0x7fffu + ((u >> 16) & 1u);            // RNE
  return (unsigned short)(u >> 16);
}

__device__ __forceinline__ float bf2f(unsigned short h) {
  return __uint_as_float((unsigned int)h << 16);
}

// pack two positive floats to bf16 pair (round half up; ties-only deviation from RNE)
__device__ __forceinline__ unsigned int pack2bf(float a, float b) {
  unsigned int ua = __float_as_uint(a) + 0x8000u;
  unsigned int ub = __float_as_uint(b) + 0x8000u;
  return __builtin_amdgcn_perm(ub, ua, 0x07060302u);  // [ua.hi16 | ub.hi16]
}

__device__ __forceinline__ void gload16(const void* g, void* l) {
  __builtin_amdgcn_global_load_lds(
      (const __attribute__((address_space(1))) unsigned int*)g,
      (__attribute__((address_space(3))) unsigned int*)l, 16, 0, 0);
}

// ---------------------------------------------------------------------------
// prep (K/V only, balanced blocks):
//  [0,512):    K 32-row half-tiles -> normalize -> LDS -> chunk-major Kfm
//              [tile64][c:32][n:64][8], coalesced 512B store runs.
//  [512,1536): V 16-row tiles -> B-frag-major Vfm via LDS transpose.
// ---------------------------------------------------------------------------
__global__ __launch_bounds__(256) void prep(
    const float* __restrict__ K, const float* __restrict__ V,
    unsigned short* __restrict__ Kfm, unsigned short* __restrict__ Vfm)
{
  __shared__ unsigned short vt[32 * 264];
  const int blk = blockIdx.x, tid = threadIdx.x;
  const int wave = tid >> 6, lane = tid & 63;
  if (blk < 512) {
    const int kt2 = blk;              // 32-row unit
    const int kt = kt2 >> 1, h = kt2 & 1;
    #pragma unroll
    for (int i = 0; i < 8; i++) {
      const int r = wave*8 + i;       // 0..31 local row
      float4 v = *(const float4*)(K + ((size_t)kt2*32 + r) * DIM + lane * 4);
      float ss = v.x*v.x + v.y*v.y + v.z*v.z + v.w*v.w;
      #pragma unroll
      for (int off = 1; off < 64; off <<= 1) ss += __shfl_xor(ss, off, 64);
      float scale = 1.0f / fmaxf(sqrtf(ss), 1e-12f);
      ushort4 o;
      o.x = f2bf(v.x*scale); o.y = f2bf(v.y*scale);
      o.z = f2bf(v.z*scale); o.w = f2bf(v.w*scale);
      *(ushort4*)(vt + r*264 + lane*4) = o;
    }
    __syncthreads();
    #pragma unroll
    for (int s = 0; s < 4; s++) {
      const int ch = tid + 256*s;          // 1024 chunks of 8 ushorts
      const int c = ch >> 5, r = ch & 31;
      const int n = h*32 + r;
      bf16x8 val = *(const bf16x8*)(vt + r*264 + c*8);
      *(bf16x8*)(Kfm + (size_t)kt*16384 + (size_t)(c*64 + n)*8) = val;
    }
  } else {
    const int NS = blk - 512;
    #pragma unroll
    for (int i = 0; i < 4; i++) {
      const int e = tid + 256*i;
      const int nl = e >> 6, d = (e & 63) * 4;
      float4 v = *(const float4*)(V + ((size_t)NS*16 + nl)*DIM + d);
      ushort4 o;
      o.x = f2bf(v.x); o.y = f2bf(v.y); o.z = f2bf(v.z); o.w = f2bf(v.w);
      *(ushort4*)(vt + nl*264 + d) = o;
    }
    __syncthreads();
    #pragma unroll
    for (int i = 0; i < 2; i++) {
      const int ch = tid + 256*i;
      const int db = ch >> 6, ln = ch & 63;
      const int row0 = (ln >> 5) * 8, dd = db*32 + (ln & 31);
      ushort4 a, b;
      a.x = vt[(row0+0)*264 + dd]; a.y = vt[(row0+1)*264 + dd];
      a.z = vt[(row0+2)*264 + dd]; a.w = vt[(row0+3)*264 + dd];
      b.x = vt[(row0+4)*264 + dd]; b.y = vt[(row0+5)*264 + dd];
      b.z = vt[(row0+6)*264 + dd]; b.w = vt[(row0+7)*264 + dd];
      size_t base = ((size_t)(NS*8 + db)*64 + ln)*8;
      *(ushort4*)(Vfm + base)     = a;
      *(ushort4*)(Vfm + base + 4) = b;
    }
  }
}

// ---------------------------------------------------------------------------
// attn: grid=512, 256 thr (4 waves), 2 blocks/CU. blk&7 -> (b,ks) for L2
// locality. Double-buffered Klds; stage(kt+1) issued at TOP of iter kt (retires
// under S via in-order vmcnt); mid barrier is lgkm-only (stage stays in flight);
// O phase pf/vf depth-1 pipelined; setprio around MFMA clusters.
// R16: Q staging stride padded to 264 (kills the 917K prologue bank conflicts).
// ---------------------------------------------------------------------------
__global__ __launch_bounds__(256, 2) void attn(
    const float* __restrict__ Qg,
    const unsigned short* __restrict__ Kfm,
    const unsigned short* __restrict__ Vfm,
    unsigned short* __restrict__ Opart, float* __restrict__ lpart)
{
  __shared__ unsigned short Klds[2][32 * 64 * 8];  // 2 x 32 KB chunk-major (both bufs also Q staging)
  __shared__ unsigned short Plds[BM * PSTRIDE];    // 8704 B row-major padded

  const int tid = threadIdx.x, wave = tid >> 6, lane = tid & 63;
  const int l15 = lane & 15, l4 = lane >> 4;
  const int blk = blockIdx.x;
  const int g = blk & 7, qt = blk >> 3;
  const int b = g >> 1, ks = g & 1;
  const int Rq0 = b*NQ + qt*BM;
  const int n0base = b*NQ + ks*(NQ/KSPLIT);
  const int mi = wave & 1, ni = wave >> 1;

  // ---- prologue: normalize 64 Q rows into padded staging (stride 264) ----
  {
    unsigned short* Qlds = &Klds[0][0];
    #pragma unroll
    for (int i = 0; i < 16; i++) {
      const int r = wave*16 + i;
      float4 v = *(const float4*)(Qg + (size_t)(Rq0 + r)*DIM + lane*4);
      float ss = v.x*v.x + v.y*v.y + v.z*v.z + v.w*v.w;
      #pragma unroll
      for (int off = 1; off < 64; off <<= 1) ss += __shfl_xor(ss, off, 64);
      float scale = (0.17677669529663687f * 1.4426950408889634f)   // SCALE*log2e
                    / fmaxf(sqrtf(ss), 1e-12f);
      ushort4 o;
      o.x = f2bf(v.x*scale); o.y = f2bf(v.y*scale);
      o.z = f2bf(v.z*scale); o.w = f2bf(v.w*scale);
      *(ushort4*)(Qlds + r*QSTRIDE + lane*4) = o;   // 64*264 = 16896 ushorts, spans into buf1 (safe pre-stage)
    }
  }
  __syncthreads();

  // Q B-frags: local row = mi*32 + mt*16 + l15, k = kg*32 + l4*8 (stride 264 -> 2-way, free)
  bf16x8 qf[2][8];
  #pragma unroll
  for (int mt = 0; mt < 2; mt++) {
    const unsigned short* qrow = &Klds[0][0] + (mi*32 + mt*16 + l15)*QSTRIDE + l4*8;
    #pragma unroll
    for (int kg = 0; kg < 8; kg++)
      qf[mt][kg] = *(const bf16x8*)(qrow + kg*32);
  }
  __syncthreads();   // all Q reads done before stage(0) overwrites buf0 (and stage(1) buf1)

  f32x16 oacc[2][2] = {};   // [mt2][dt]
  float lacc[2] = {};       // [mt]

  auto stage = [&](int kt_) {
    unsigned short* dst = &Klds[kt_ & 1][0];
    const unsigned short* src = Kfm + (size_t)((n0base + kt_*BN) >> 6) * (32*64*8);
    #pragma unroll
    for (int jj = 0; jj < 4; jj++) {
      const int c = wave*8 + jj*2;      // 8 chunks (1 KB each) per wave
      gload16(src + (size_t)c*512 + lane*8,     dst + (size_t)c*512);
      gload16(src + (size_t)(c+1)*512 + lane*8, dst + (size_t)(c+1)*512);
    }
  };

  stage(0);

  for (int kt = 0; kt < NITER; kt++) {
    // top barrier: vmcnt(0) drains stage(kt) (already mostly retired by O(kt-1)'s
    // in-order vf waits); lgkmcnt(0) covers prev O's Plds reads vs this P's writes.
    __syncthreads();

    // issue next tile's stage NOW: it is older than all of this iter's VMEM, so it
    // retires for free under S+P (no VMEM in S) instead of stalling O's first MFMA.
    if (kt + 1 < NITER) stage(kt + 1);
    __builtin_amdgcn_sched_barrier(0);   // keep stage issue ahead of S phase

    const unsigned short* kb = &Klds[kt & 1][0];

    // ---- S^T = Khat Qhat^T (scale folded into Q) ----
    f32x4 sacc[2][2] = {};   // [nt][mt]
    #pragma unroll
    for (int kg = 0; kg < 8; kg++) {
      bf16x8 kf[2];
      #pragma unroll
      for (int nt = 0; nt < 2; nt++) {
        const int nrow = ni*32 + nt*16 + l15;
        const int c = kg*4 + l4;
        kf[nt] = *(const bf16x8*)(kb + ((size_t)(c*64 + nrow))*8);
      }
      __builtin_amdgcn_s_setprio(1);
      #pragma unroll
      for (int nt = 0; nt < 2; nt++)
        #pragma unroll
        for (int mt = 0; mt < 2; mt++)
          sacc[nt][mt] = __builtin_amdgcn_mfma_f32_16x16x32_bf16(
              kf[nt], qf[mt][kg], sacc[nt][mt], 0, 0, 0);
      __builtin_amdgcn_s_setprio(0);
    }

    // ---- P = exp2(S); row-sums; packed b64 writes to Plds[m][n] ----
    #pragma unroll
    for (int nt = 0; nt < 2; nt++)
      #pragma unroll
      for (int mt = 0; mt < 2; mt++) {
        float p0 = __builtin_amdgcn_exp2f(sacc[nt][mt][0]);
        float p1 = __builtin_amdgcn_exp2f(sacc[nt][mt][1]);
        float p2 = __builtin_amdgcn_exp2f(sacc[nt][mt][2]);
        float p3 = __builtin_amdgcn_exp2f(sacc[nt][mt][3]);
        lacc[mt] += (p0 + p1) + (p2 + p3);
        uint2 pk;
        pk.x = pack2bf(p0, p1);
        pk.y = pack2bf(p2, p3);
        const int m = mi*32 + mt*16 + l15;
        const int n = ni*32 + nt*16 + 4*l4;
        *(uint2*)(Plds + m*PSTRIDE + n) = pk;
      }

    // mid barrier: P visible (lgkm only) -- stage(kt+1) stays in flight (T4).
    asm volatile("s_waitcnt lgkmcnt(0)" ::: "memory");
    __builtin_amdgcn_s_barrier();
    __builtin_amdgcn_sched_barrier(0);   // no O loads hoisted above the barrier

    // ---- O += P V (depth-1 pipelined pf/vf) ----
    const int NB0 = (n0base + kt*BN) >> 4;
    bf16x8 pf[2][2], vf[2][2];
    #pragma unroll
    for (int mt2 = 0; mt2 < 2; mt2++)
      pf[0][mt2] = *(const bf16x8*)(Plds + (mt2*32 + (lane & 31))*PSTRIDE
                                    + 8*(lane >> 5));
    #pragma unroll
    for (int dt = 0; dt < 2; dt++)
      vf[0][dt] = *(const bf16x8*)(Vfm + ((size_t)(NB0*8 + wave*2 + dt)*64 + lane)*8);
    #pragma unroll
    for (int kstep = 0; kstep < 4; kstep++) {
      const int cb = kstep & 1;
      if (kstep < 3) {
        #pragma unroll
        for (int mt2 = 0; mt2 < 2; mt2++)
          pf[cb^1][mt2] = *(const bf16x8*)(Plds + (mt2*32 + (lane & 31))*PSTRIDE
                                           + (kstep+1)*16 + 8*(lane >> 5));
        #pragma unroll
        for (int dt = 0; dt < 2; dt++)
          vf[cb^1][dt] = *(const bf16x8*)(Vfm
              + ((size_t)((NB0 + kstep + 1)*8 + wave*2 + dt)*64 + lane)*8);
      }
      __builtin_amdgcn_s_setprio(1);
      #pragma unroll
      for (int mt2 = 0; mt2 < 2; mt2++)
        #pragma unroll
        for (int dt = 0; dt < 2; dt++)
          oacc[mt2][dt] = __builtin_amdgcn_mfma_f32_32x32x16_bf16(
              pf[cb][mt2], vf[cb][dt], oacc[mt2][dt], 0, 0, 0);
      __builtin_amdgcn_s_setprio(0);
    }
  }

  // ---- epilogue: l row-sums (reduce over l4 groups) ----
  #pragma unroll
  for (int mt = 0; mt < 2; mt++) {
    float s = lacc[mt];
    s += __shfl_xor(s, 16, 64);
    s += __shfl_xor(s, 32, 64);
    if (l4 == 0)
      lpart[(size_t)(ks*2 + ni)*NROWS + Rq0 + mi*32 + mt*16 + l15] = s;
  }

  // ---- epilogue: O stores (bf16) ----
  #pragma unroll
  for (int mt2 = 0; mt2 < 2; mt2++)
    #pragma unroll
    for (int dt = 0; dt < 2; dt++)
      #pragma unroll
      for (int reg = 0; reg < 16; reg++) {
        const int m = mt2*32 + 4*(lane >> 5) + (reg & 3) + 8*(reg >> 2);
        const int d = wave*64 + dt*32 + (lane & 31);
        Opart[((size_t)(ks*NROWS + Rq0 + m))*DIM + d] = f2bf(oacc[mt2][dt][reg]);
      }
}

// ---------------------------------------------------------------------------
// combine: out = (O0+O1) / (l0+l1+l2+l3), Opart in bf16
// ---------------------------------------------------------------------------
__global__ __launch_bounds__(256) void combine(
    const unsigned short* __restrict__ Opart, const float* __restrict__ lpart,
    float* __restrict__ out)
{
  const size_t idx = (size_t)blockIdx.x*256 + threadIdx.x;
  const size_t e = idx*4;
  const int R = (int)(e >> 8);
  ushort4 o0 = *(const ushort4*)(Opart + e);
  ushort4 o1 = *(const ushort4*)(Opart + (size_t)NROWS*DIM + e);
  float ls = lpart[R] + lpart[NROWS + R] + lpart[2*NROWS + R] + lpart[3*NROWS + R];
  float inv = 1.0f / ls;
  float4 o;
  o.x = (bf2f(o0.x) + bf2f(o1.x))*inv;
  o.y = (bf2f(o0.y) + bf2f(o1.y))*inv;
  o.z = (bf2f(o0.z) + bf2f(o1.z))*inv;
  o.w = (bf2f(o0.w) + bf2f(o1.w))*inv;
  *(float4*)(out + e) = o;
}

extern "C" void kernel_launch(void* const* d_in, const int* in_sizes, int n_in,
                              void* d_out, int out_size, void* d_ws, size_t ws_size,
                              hipStream_t stream) {
  const float* Q = (const float*)d_in[0];
  const float* K = (const float*)d_in[1];
  const float* V = (const float*)d_in[2];
  char* ws = (char*)d_ws;
  // ws layout: Kfm 8 MiB | Vfm 8 MiB | Opart(bf16) 16 MiB | lpart 256 KiB
  unsigned short* Kfm   = (unsigned short*)(ws);
  unsigned short* Vfm   = (unsigned short*)(ws + 8388608);
  unsigned short* Opart = (unsigned short*)(ws + 16777216);
  float* lpart = (float*)(ws + 33554432);

  prep<<<1536, 256, 0, stream>>>(K, V, Kfm, Vfm);
  attn<<<512, 256, 0, stream>>>(Q, Kfm, Vfm, Opart, lpart);
  combine<<<4096, 256, 0, stream>>>(Opart, lpart, (float*)d_out);
}